// Round 2
// baseline (1750.641 us; speedup 1.0000x reference)
//
#include <hip/hip_runtime.h>
#include <math.h>

// Problem constants
#define BB 2
#define SS 2048
#define EE 2048
#define HH 16
#define KVH 4
#define HD 128

typedef __attribute__((ext_vector_type(8))) short short8;
typedef __attribute__((ext_vector_type(4))) float f32x4;

__device__ __forceinline__ short f2b(float f) {
  unsigned u = __float_as_uint(f);
  unsigned r = (u + 0x7fffu + ((u >> 16) & 1u)) >> 16;
  return (short)r;
}

__device__ __forceinline__ void async_load16(const void* g, void* l) {
  __builtin_amdgcn_global_load_lds(
      (const __attribute__((address_space(1))) void*)g,
      (__attribute__((address_space(3))) void*)l, 16, 0, 0);
}

// RoPE freq replicating reference fp32 overflow: freqs[jp] = 1/theta^(2jp);
// theta^8 -> inf -> 0 (exp2f underflows likewise).
__device__ __forceinline__ float rope_freq(int jp) {
  return exp2f(-(float)(2 * jp) * 16.609640474436812f);
}

// ---------------- x: f32 -> bf16, elementwise ----------------
__global__ void f32_to_bf16(const float* __restrict__ in, short* __restrict__ out) {
  int i = (blockIdx.x * 256 + threadIdx.x) * 8;
  float4 a = *(const float4*)(in + i);
  float4 b = *(const float4*)(in + i + 4);
  short8 c;
  c[0] = f2b(a.x); c[1] = f2b(a.y); c[2] = f2b(a.z); c[3] = f2b(a.w);
  c[4] = f2b(b.x); c[5] = f2b(b.y); c[6] = f2b(b.z); c[7] = f2b(b.w);
  *(short8*)(out + i) = c;
}

// ---------------- weight transpose + f32->bf16: (K,N) f32 -> (N,K) bf16 ----
__global__ void transpose_f2b(const float* __restrict__ in, short* __restrict__ out,
                              int K, int N) {
  __shared__ short tile[32][33];
  int n0 = blockIdx.x * 32, k0 = blockIdx.y * 32;
  int tx = threadIdx.x, ty = threadIdx.y;  // 32 x 8
#pragma unroll
  for (int i = 0; i < 32; i += 8)
    tile[ty + i][tx] = f2b(in[(size_t)(k0 + ty + i) * N + n0 + tx]);
  __syncthreads();
#pragma unroll
  for (int i = 0; i < 32; i += 8)
    out[(size_t)(n0 + ty + i) * K + k0 + tx] = tile[tx][ty + i];
}

// -------------------- QKV GEMM + bias + RoPE --------------------
// A: xb (4096 x 2048) bf16. Bt: packed bf16 [wq^T; wk^T; wv^T] (3072 x 2048).
// 256x256 tile, 8 waves (2x4 of 128x64), BK=32, 2-phase LDS double-buffer
// (T3 minimum recipe: stage next tile, compute current, one barrier/tile).
// Traffic floor: 192 blocks x 2 MB = 384 MB (vs 768 MB at 128^2) -- the
// window is byte-proportional at ~5.2 TB/s, so bytes are the lever.
// BK=32 (64 B rows): a wave's 64 b128 lane-reads tile a contiguous 1 KB ->
// bank-conflict-free without swizzle. Default block->XCD mapping kept
// (2 m-tiles x 12 n-tiles per XCD; per-k-step footprint 224 KB << 4 MB L2).
__global__ __launch_bounds__(512, 2) void gemm_qkv(
    const short* __restrict__ A, const short* __restrict__ Bt,
    const float* __restrict__ bq, const float* __restrict__ bk,
    const float* __restrict__ bv,
    short* __restrict__ qbuf, short* __restrict__ kbuf, short* __restrict__ vtr) {
  // K-loop uses first 64 KB (2 x {A 16 KB, B 16 KB}); epilogue restages the
  // full 256 x 264-pitch tile (135 KB). 1 block/CU either way (VGPR-bound).
  __shared__ __align__(16) short Sm[256 * 264];
  const int K = EE;
  int t = threadIdx.x, lane = t & 63, w = t >> 6;
  int lj = lane & 15, lr = lane >> 4;
  int wm2 = (w >> 2) * 128, wn2 = (w & 3) * 64;
  int m0 = blockIdx.x * 256, n0 = blockIdx.y * 256;
  const short* Ab = A + (size_t)m0 * K;
  const short* Bb = Bt + (size_t)n0 * K;
  // staging: thread t covers row q*128+(t>>2), cols (t&3)*8..+8 (16 B)
  int srow = t >> 2, scol = (t & 3) * 8;
  char* ldsA = (char*)Sm + w * 1024;           // wave-uniform; HW adds lane*16
  char* ldsB = (char*)Sm + 16384 + w * 1024;
  f32x4 acc[8][4] = {};
  // prologue: stage k-tile 0 into buffer 0
#pragma unroll
  for (int q = 0; q < 2; q++) {
    async_load16(Ab + (size_t)(q * 128 + srow) * K + scol, ldsA + q * 8192);
    async_load16(Bb + (size_t)(q * 128 + srow) * K + scol, ldsB + q * 8192);
  }
  __syncthreads();
  int cur = 0;
  for (int kt = 0; kt < 63; kt++) {
    int nxt = cur ^ 1;
    int k0 = (kt + 1) * 32;
    // issue next-tile loads first: they fly during ds_read + MFMA below
#pragma unroll
    for (int q = 0; q < 2; q++) {
      async_load16(Ab + (size_t)(q * 128 + srow) * K + k0 + scol,
                   ldsA + nxt * 32768 + q * 8192);
      async_load16(Bb + (size_t)(q * 128 + srow) * K + k0 + scol,
                   ldsB + nxt * 32768 + q * 8192);
    }
    const short* Ac = Sm + cur * 16384;
    const short* Bc = Sm + cur * 16384 + 8192;
    short8 a[8], b[4];
#pragma unroll
    for (int i = 0; i < 8; i++)
      a[i] = *(const short8*)&Ac[(wm2 + i * 16 + lj) * 32 + lr * 8];
#pragma unroll
    for (int j = 0; j < 4; j++)
      b[j] = *(const short8*)&Bc[(wn2 + j * 16 + lj) * 32 + lr * 8];
#pragma unroll
    for (int i = 0; i < 8; i++)
#pragma unroll
      for (int j = 0; j < 4; j++)
        acc[i][j] = __builtin_amdgcn_mfma_f32_16x16x32_bf16(a[i], b[j], acc[i][j], 0, 0, 0);
    __syncthreads();  // drains vmcnt(0)+lgkmcnt(0): next buffer ready, reads done
    cur = nxt;
  }
  {  // final k-tile: compute only
    const short* Ac = Sm + cur * 16384;
    const short* Bc = Sm + cur * 16384 + 8192;
    short8 a[8], b[4];
#pragma unroll
    for (int i = 0; i < 8; i++)
      a[i] = *(const short8*)&Ac[(wm2 + i * 16 + lj) * 32 + lr * 8];
#pragma unroll
    for (int j = 0; j < 4; j++)
      b[j] = *(const short8*)&Bc[(wn2 + j * 16 + lj) * 32 + lr * 8];
#pragma unroll
    for (int i = 0; i < 8; i++)
#pragma unroll
      for (int j = 0; j < 4; j++)
        acc[i][j] = __builtin_amdgcn_mfma_f32_16x16x32_bf16(a[i], b[j], acc[i][j], 0, 0, 0);
  }
  __syncthreads();  // all ds_reads done before epilogue staging overwrites LDS
  // ---- stage epilogue tile into LDS (pitch 264), then coalesced write ----
  if (n0 < 2048) {  // Q: bias + rope, row-major (s_loc, d)
#pragma unroll
    for (int j = 0; j < 4; j++) {
      int dl = wn2 + j * 16 + lj;
      float bias = bq[n0 + dl];
      float freq = rope_freq((dl & 127) >> 1);
      bool odd = (dl & 1) != 0;
#pragma unroll
      for (int i = 0; i < 8; i++)
#pragma unroll
        for (int r = 0; r < 4; r++) {
          int mloc = wm2 + i * 16 + lr * 4 + r;
          int s = (m0 + mloc) & (SS - 1);
          float val = acc[i][j][r] + bias;
          float other = __shfl_xor(val, 1, 64);
          float ang = (float)s * freq;
          float cs = cosf(ang), sn = sinf(ang);
          float res = odd ? (other * sn + val * cs) : (val * cs - other * sn);
          Sm[mloc * 264 + dl] = f2b(res);
        }
    }
  } else if (n0 < 2560) {  // K: bias + rope, row-major (s_loc, d)
    int base = n0 - 2048;
#pragma unroll
    for (int j = 0; j < 4; j++) {
      int dl = wn2 + j * 16 + lj;
      float bias = bk[base + dl];
      float freq = rope_freq((dl & 127) >> 1);
      bool odd = (dl & 1) != 0;
#pragma unroll
      for (int i = 0; i < 8; i++)
#pragma unroll
        for (int r = 0; r < 4; r++) {
          int mloc = wm2 + i * 16 + lr * 4 + r;
          int s = (m0 + mloc) & (SS - 1);
          float val = acc[i][j][r] + bias;
          float other = __shfl_xor(val, 1, 64);
          float ang = (float)s * freq;
          float cs = cosf(ang), sn = sinf(ang);
          float res = odd ? (other * sn + val * cs) : (val * cs - other * sn);
          Sm[mloc * 264 + dl] = f2b(res);
        }
    }
  } else {  // V: bias, stage TRANSPOSED (d, s_loc)
    int base = n0 - 2560;
#pragma unroll
    for (int j = 0; j < 4; j++) {
      int dl = wn2 + j * 16 + lj;
      float bias = bv[base + dl];
#pragma unroll
      for (int i = 0; i < 8; i++)
#pragma unroll
        for (int r = 0; r < 4; r++) {
          int mloc = wm2 + i * 16 + lr * 4 + r;
          Sm[dl * 264 + mloc] = f2b(acc[i][j][r] + bias);
        }
    }
  }
  __syncthreads();
  int r0 = t >> 5, ch = t & 31;  // 16 rows/sweep x 512 B rows
  if (n0 < 2048) {
#pragma unroll
    for (int p = 0; p < 16; p++) {
      int row = p * 16 + r0;  // s_loc
      *(short8*)(qbuf + (size_t)(m0 + row) * 2048 + n0 + ch * 8) =
          *(const short8*)&Sm[row * 264 + ch * 8];
    }
  } else if (n0 < 2560) {
    int base = n0 - 2048;
    int bb = m0 >> 11, s0 = m0 & (SS - 1);
    int col = base + ch * 8;  // 256-wide tile = 2 kv heads
    int kvh = col >> 7, d = col & 127;
    short* dst = kbuf + ((size_t)(bb * KVH + kvh) * SS + s0) * HD + d;
#pragma unroll
    for (int p = 0; p < 16; p++) {
      int row = p * 16 + r0;  // s_loc
      *(short8*)(dst + (size_t)row * HD) = *(const short8*)&Sm[row * 264 + ch * 8];
    }
  } else {
    int base = n0 - 2560;
    int bb = m0 >> 11, s0 = m0 & (SS - 1);
#pragma unroll
    for (int p = 0; p < 16; p++) {
      int dl = p * 16 + r0;  // d_local
      int col = base + dl;
      int kvh = col >> 7, d = col & 127;
      *(short8*)(vtr + ((size_t)(bb * KVH + kvh) * HD + d) * SS + s0 + ch * 8) =
          *(const short8*)&Sm[dl * 264 + ch * 8];
    }
  }
}

// -------------------- flash attention (causal, GQA) --------------------
// XCD-chunked swizzle: 1024 blocks / 8 XCDs = 128-block chunks. Chunk c maps
// exactly to one (batch, kvh-group): its whole K+V working set is 1 MB,
// L2-resident across all 128 blocks of the XCD (helped in R0: net -58 us
// with gemm_out swizzle).
__global__ __launch_bounds__(256) void attn_kernel(
    const short* __restrict__ qb, const short* __restrict__ kb,
    const short* __restrict__ vt, short* __restrict__ ao) {
  __shared__ __align__(16) short Kl[64 * 128];     // (key, hd)
  __shared__ __align__(16) short Vl[128 * 64];     // (hd, key)
  __shared__ __align__(16) short Pl[4 * 16 * 64];  // per-wave P
  int t = threadIdx.x, lane = t & 63, w = t >> 6;
  int lj = lane & 15, lr = lane >> 4;
  int id = blockIdx.x + (blockIdx.y << 5) + (blockIdx.z << 9);  // 1024 blocks
  int swz = (id & 7) * 128 + (id >> 3);
  int qt = swz & 31, h = (swz >> 5) & 15, b = swz >> 9;
  int kvh = h >> 2;  // REP = 4
  int qb0 = qt * 64;
  const short* qbase = qb + (size_t)(b * SS) * 2048 + h * HD;
  const short* kbase = kb + (size_t)(b * KVH + kvh) * SS * HD;
  const short* vbase = vt + (size_t)(b * KVH + kvh) * HD * SS;
  short8 aq[4];
  int sq = qb0 + w * 16 + lj;
#pragma unroll
  for (int kk = 0; kk < 4; kk++)
    aq[kk] = *(const short8*)(qbase + (size_t)sq * 2048 + kk * 32 + lr * 8);
  f32x4 O[8] = {};
  const float NEG = -1e30f;
  float mrow[4] = {NEG, NEG, NEG, NEG};
  float lrow[4] = {0.f, 0.f, 0.f, 0.f};
  const float scale = 0.088388347648318447f;  // 1/sqrt(128)
  int nkt = qt + 1;
  for (int kt = 0; kt < nkt; ++kt) {
    short8 gk[4], gv[4];
#pragma unroll
    for (int i = 0; i < 4; i++) {
      gk[i] = *(const short8*)(kbase + (size_t)(kt * 64 + i * 16 + (t >> 4)) * HD + (t & 15) * 8);
      gv[i] = *(const short8*)(vbase + (size_t)(i * 32 + (t >> 3)) * SS + kt * 64 + (t & 7) * 8);
    }
#pragma unroll
    for (int i = 0; i < 4; i++) {
      *(short8*)&Kl[(i * 16 + (t >> 4)) * 128 + (t & 15) * 8] = gk[i];
      *(short8*)&Vl[(i * 32 + (t >> 3)) * 64 + (t & 7) * 8] = gv[i];
    }
    __syncthreads();
    f32x4 S[4];
#pragma unroll
    for (int nt = 0; nt < 4; nt++) {
      f32x4 sc = {};
#pragma unroll
      for (int kk = 0; kk < 4; kk++) {
        short8 bk_ = *(const short8*)&Kl[(nt * 16 + lj) * 128 + kk * 32 + lr * 8];
        sc = __builtin_amdgcn_mfma_f32_16x16x32_bf16(aq[kk], bk_, sc, 0, 0, 0);
      }
      S[nt] = sc;
    }
    int rowg = qb0 + w * 16 + lr * 4;
#pragma unroll
    for (int nt = 0; nt < 4; nt++) {
      int colg = kt * 64 + nt * 16 + lj;
#pragma unroll
      for (int r = 0; r < 4; r++) {
        float v = S[nt][r] * scale;
        if (colg > rowg + r) v = NEG;  // finite mask; exp underflows to 0
        S[nt][r] = v;
      }
    }
    float alpha[4];
#pragma unroll
    for (int r = 0; r < 4; r++) {
      float m_ = fmaxf(fmaxf(S[0][r], S[1][r]), fmaxf(S[2][r], S[3][r]));
#pragma unroll
      for (int off = 1; off < 16; off <<= 1) m_ = fmaxf(m_, __shfl_xor(m_, off, 64));
      float mn = fmaxf(mrow[r], m_);
      alpha[r] = __expf(mrow[r] - mn);
      mrow[r] = mn;
    }
    float ls[4] = {0.f, 0.f, 0.f, 0.f};
#pragma unroll
    for (int nt = 0; nt < 4; nt++)
#pragma unroll
      for (int r = 0; r < 4; r++) {
        float p = __expf(S[nt][r] - mrow[r]);
        ls[r] += p;
        Pl[(w * 16 + lr * 4 + r) * 64 + nt * 16 + lj] = f2b(p);
      }
#pragma unroll
    for (int r = 0; r < 4; r++) {
      float s_ = ls[r];
#pragma unroll
      for (int off = 1; off < 16; off <<= 1) s_ += __shfl_xor(s_, off, 64);
      lrow[r] = lrow[r] * alpha[r] + s_;
    }
#pragma unroll
    for (int jt = 0; jt < 8; jt++)
#pragma unroll
      for (int r = 0; r < 4; r++) O[jt][r] *= alpha[r];
#pragma unroll
    for (int kk = 0; kk < 2; kk++) {
      short8 ap = *(const short8*)&Pl[(w * 16 + lj) * 64 + kk * 32 + lr * 8];
#pragma unroll
      for (int jt = 0; jt < 8; jt++) {
        short8 bv_ = *(const short8*)&Vl[(jt * 16 + lj) * 64 + kk * 32 + lr * 8];
        O[jt] = __builtin_amdgcn_mfma_f32_16x16x32_bf16(ap, bv_, O[jt], 0, 0, 0);
      }
    }
    __syncthreads();
  }
  size_t obase = (size_t)(b * SS + qb0 + w * 16) * 2048 + h * HD;
#pragma unroll
  for (int jt = 0; jt < 8; jt++)
#pragma unroll
    for (int r = 0; r < 4; r++) {
      int row = lr * 4 + r;
      ao[obase + (size_t)row * 2048 + jt * 16 + lj] = f2b(O[jt][r] / lrow[r]);
    }
}

// -------------- output projection GEMM + bias (f32 output) --------------
// XCD-chunked swizzle kept (part of R0's net win on non-qkv kernels).
__global__ __launch_bounds__(256) void gemm_out(
    const short* __restrict__ A, const short* __restrict__ Bt,
    const float* __restrict__ bo, float* __restrict__ out) {
  __shared__ __align__(16) short Al[128 * 32];
  __shared__ __align__(16) short Bl[128 * 32];
  const int K = EE;
  int t = threadIdx.x, lane = t & 63, w = t >> 6;
  int wm = (w >> 1) * 64, wn = (w & 1) * 64;
  int id = blockIdx.y * 32 + blockIdx.x;   // 512 blocks, x fastest
  int swz = (id & 7) * 64 + (id >> 3);
  int m0 = (swz & 31) * 128, n0 = (swz >> 5) * 128;
  const short* Ab = A + (size_t)m0 * K;
  const short* Bb = Bt + (size_t)n0 * K;
  int sr = t >> 2, sc = (t & 3) * 8;
  char* AlB = (char*)Al + w * 1024;
  char* BlB = (char*)Bl + w * 1024;
  f32x4 acc[4][4] = {};
  for (int k0 = 0; k0 < K; k0 += 32) {
    async_load16(Ab + (size_t)sr * K + k0 + sc, AlB);
    async_load16(Ab + (size_t)(64 + sr) * K + k0 + sc, AlB + 4096);
    async_load16(Bb + (size_t)sr * K + k0 + sc, BlB);
    async_load16(Bb + (size_t)(64 + sr) * K + k0 + sc, BlB + 4096);
    __syncthreads();
    short8 a[4], b[4];
#pragma unroll
    for (int i = 0; i < 4; i++)
      a[i] = *(const short8*)&Al[(wm + i * 16 + (lane & 15)) * 32 + (lane >> 4) * 8];
#pragma unroll
    for (int j = 0; j < 4; j++)
      b[j] = *(const short8*)&Bl[(wn + j * 16 + (lane & 15)) * 32 + (lane >> 4) * 8];
#pragma unroll
    for (int i = 0; i < 4; i++)
#pragma unroll
      for (int j = 0; j < 4; j++)
        acc[i][j] = __builtin_amdgcn_mfma_f32_16x16x32_bf16(a[i], b[j], acc[i][j], 0, 0, 0);
    __syncthreads();
  }
#pragma unroll
  for (int j = 0; j < 4; j++) {
    int n = n0 + wn + j * 16 + (lane & 15);
    float bias = bo[n];
#pragma unroll
    for (int i = 0; i < 4; i++)
#pragma unroll
      for (int r = 0; r < 4; r++) {
        int m = m0 + wm + i * 16 + (lane >> 4) * 4 + r;
        out[(size_t)m * 2048 + n] = acc[i][j][r] + bias;
      }
  }
}

extern "C" void kernel_launch(void* const* d_in, const int* in_sizes, int n_in,
                              void* d_out, int out_size, void* d_ws, size_t ws_size,
                              hipStream_t stream) {
  const float* x  = (const float*)d_in[0];
  const float* wq = (const float*)d_in[1];
  const float* bq = (const float*)d_in[2];
  const float* wk = (const float*)d_in[3];
  const float* bk = (const float*)d_in[4];
  const float* wv = (const float*)d_in[5];
  const float* bv = (const float*)d_in[6];
  const float* wo = (const float*)d_in[7];
  const float* bo = (const float*)d_in[8];
  float* out = (float*)d_out;  // f32 output per reference dtype

  // bf16 workspace, ~63 MB used. xb_ aliases ao_ (disjoint lifetime).
  short* W1t = (short*)d_ws;                    // 3072*2048
  short* Wot = W1t + (size_t)3072 * 2048;       // 2048*2048
  short* qb_ = Wot + (size_t)2048 * 2048;       // 4096*2048
  short* kb_ = qb_ + (size_t)4096 * 2048;       // 2*4*2048*128
  short* vt_ = kb_ + (size_t)4096 * 512;        // 2*4*128*2048
  short* ao_ = vt_ + (size_t)4096 * 512;        // 4096*2048
  short* xb_ = ao_;                             // alias (disjoint lifetime)

  dim3 tb(32, 8);
  f32_to_bf16<<<4096, 256, 0, stream>>>(x, xb_);
  transpose_f2b<<<dim3(64, 64), tb, 0, stream>>>(wq, W1t, 2048, 2048);
  transpose_f2b<<<dim3(16, 64), tb, 0, stream>>>(wk, W1t + (size_t)2048 * 2048, 2048, 512);
  transpose_f2b<<<dim3(16, 64), tb, 0, stream>>>(wv, W1t + (size_t)2560 * 2048, 2048, 512);
  transpose_f2b<<<dim3(64, 64), tb, 0, stream>>>(wo, Wot, 2048, 2048);

  gemm_qkv<<<dim3(16, 12), 512, 0, stream>>>(xb_, W1t, bq, bk, bv, qb_, kb_, vt_);
  attn_kernel<<<dim3(32, 16, 2), 256, 0, stream>>>(qb_, kb_, vt_, ao_);
  gemm_out<<<dim3(32, 16), 256, 0, stream>>>(ao_, Wot, bo, out);
}

// Round 3
// 982.775 us; speedup vs baseline: 1.7813x; 1.7813x over previous
//
#include <hip/hip_runtime.h>
#include <math.h>

// Problem constants
#define BB 2
#define SS 2048
#define EE 2048
#define HH 16
#define KVH 4
#define HD 128

typedef __attribute__((ext_vector_type(8))) short short8;
typedef __attribute__((ext_vector_type(4))) float f32x4;

__device__ __forceinline__ short f2b(float f) {
  unsigned u = __float_as_uint(f);
  unsigned r = (u + 0x7fffu + ((u >> 16) & 1u)) >> 16;
  return (short)r;
}

__device__ __forceinline__ void async_load16(const void* g, void* l) {
  __builtin_amdgcn_global_load_lds(
      (const __attribute__((address_space(1))) void*)g,
      (__attribute__((address_space(3))) void*)l, 16, 0, 0);
}

// RoPE freq replicating reference fp32 overflow: freqs[jp] = 1/theta^(2jp);
// theta^8 -> inf -> 0 (exp2f underflows likewise).
__device__ __forceinline__ float rope_freq(int jp) {
  return exp2f(-(float)(2 * jp) * 16.609640474436812f);
}

// ---------------- x: f32 -> bf16, elementwise ----------------
__global__ void f32_to_bf16(const float* __restrict__ in, short* __restrict__ out) {
  int i = (blockIdx.x * 256 + threadIdx.x) * 8;
  float4 a = *(const float4*)(in + i);
  float4 b = *(const float4*)(in + i + 4);
  short8 c;
  c[0] = f2b(a.x); c[1] = f2b(a.y); c[2] = f2b(a.z); c[3] = f2b(a.w);
  c[4] = f2b(b.x); c[5] = f2b(b.y); c[6] = f2b(b.z); c[7] = f2b(b.w);
  *(short8*)(out + i) = c;
}

// ---------------- weight transpose + f32->bf16: (K,N) f32 -> (N,K) bf16 ----
__global__ void transpose_f2b(const float* __restrict__ in, short* __restrict__ out,
                              int K, int N) {
  __shared__ short tile[32][33];
  int n0 = blockIdx.x * 32, k0 = blockIdx.y * 32;
  int tx = threadIdx.x, ty = threadIdx.y;  // 32 x 8
#pragma unroll
  for (int i = 0; i < 32; i += 8)
    tile[ty + i][tx] = f2b(in[(size_t)(k0 + ty + i) * N + n0 + tx]);
  __syncthreads();
#pragma unroll
  for (int i = 0; i < 32; i += 8)
    out[(size_t)(n0 + ty + i) * K + k0 + tx] = tile[tx][ty + i];
}

// -------------------- QKV GEMM + bias + RoPE --------------------
// A: xb (4096 x 2048) bf16. Bt: packed bf16 [wq^T; wk^T; wv^T] (3072 x 2048).
// BM=256 x BN=128, 8 waves (4x2 of 64x64), BK=64, single-buffer loop
// (R0's proven 2-barrier structure that sustained 5.18 TB/s window BW).
// Byte floor: 384 blocks x (1 MB A + 0.5 MB B) = 576 MB (vs 768 at 128^2).
// R1 lessons applied: 128 B row segments (BK=64, 8 lanes/row -> no line
// overfetch), 384 blocks >= 256 CUs, LDS 69.6 KB -> 2 blocks/CU.
__global__ __launch_bounds__(512, 4) void gemm_qkv(
    const short* __restrict__ A, const short* __restrict__ Bt,
    const float* __restrict__ bq, const float* __restrict__ bk,
    const float* __restrict__ bv,
    short* __restrict__ qbuf, short* __restrict__ kbuf, short* __restrict__ vtr) {
  // K-loop uses 48 KB (A 256x64 = 32 KB, B 128x64 = 16 KB); epilogue
  // restages 256 x 136-pitch (69.6 KB) -> LDS block 69632 B, 2 blocks/CU.
  __shared__ __align__(16) short Sm[256 * 136];
  short* Bl = Sm + 16384;  // B rows after A region (16384 shorts = 32 KB)
  const int K = EE;
  int t = threadIdx.x, lane = t & 63, w = t >> 6;
  int lj = lane & 15, lr = lane >> 4;
  int wm = (w >> 1) * 64, wn = (w & 1) * 64;  // 4 m-waves x 2 n-waves
  int m0 = blockIdx.x * 256, n0 = blockIdx.y * 128;
  const short* Ab = A + (size_t)m0 * K;
  const short* Bb = Bt + (size_t)n0 * K;
  // staging: thread t covers row q*64+(t>>3), cols (t&7)*8 (8 lanes = 128 B)
  int srow = t >> 3, scol = (t & 7) * 8;
  char* ldsA = (char*)Sm + w * 1024;            // wave-uniform; HW adds lane*16
  char* ldsB = (char*)Sm + 32768 + w * 1024;
  f32x4 acc[4][4] = {};
  for (int k0 = 0; k0 < K; k0 += 64) {
#pragma unroll
    for (int q = 0; q < 4; q++)
      async_load16(Ab + (size_t)(q * 64 + srow) * K + k0 + scol, ldsA + q * 8192);
#pragma unroll
    for (int q = 0; q < 2; q++)
      async_load16(Bb + (size_t)(q * 64 + srow) * K + k0 + scol, ldsB + q * 8192);
    __syncthreads();
    short8 a0[4], a1[4], b0[4], b1[4];
#pragma unroll
    for (int i = 0; i < 4; i++) {
      a0[i] = *(const short8*)&Sm[(wm + i * 16 + lj) * 64 + lr * 8];
      a1[i] = *(const short8*)&Sm[(wm + i * 16 + lj) * 64 + 32 + lr * 8];
    }
#pragma unroll
    for (int j = 0; j < 4; j++) {
      b0[j] = *(const short8*)&Bl[(wn + j * 16 + lj) * 64 + lr * 8];
      b1[j] = *(const short8*)&Bl[(wn + j * 16 + lj) * 64 + 32 + lr * 8];
    }
#pragma unroll
    for (int i = 0; i < 4; i++)
#pragma unroll
      for (int j = 0; j < 4; j++) {
        acc[i][j] = __builtin_amdgcn_mfma_f32_16x16x32_bf16(a0[i], b0[j], acc[i][j], 0, 0, 0);
        acc[i][j] = __builtin_amdgcn_mfma_f32_16x16x32_bf16(a1[i], b1[j], acc[i][j], 0, 0, 0);
      }
    __syncthreads();
  }
  // ---- stage epilogue tile into LDS (pitch 136), then coalesced write ----
  if (n0 < 2048) {  // Q: bias + rope, row-major (s_loc, d)
#pragma unroll
    for (int j = 0; j < 4; j++) {
      int d = wn + j * 16 + lj;
      float bias = bq[n0 + d];
      float freq = rope_freq(d >> 1);
      bool odd = (d & 1) != 0;
#pragma unroll
      for (int i = 0; i < 4; i++)
#pragma unroll
        for (int r = 0; r < 4; r++) {
          int mloc = wm + i * 16 + lr * 4 + r;
          int s = (m0 + mloc) & (SS - 1);
          float val = acc[i][j][r] + bias;
          float other = __shfl_xor(val, 1, 64);
          float ang = (float)s * freq;
          float cs = cosf(ang), sn = sinf(ang);
          float res = odd ? (other * sn + val * cs) : (val * cs - other * sn);
          Sm[mloc * 136 + d] = f2b(res);
        }
    }
  } else if (n0 < 2560) {  // K: bias + rope, row-major (s_loc, d)
    int base = n0 - 2048;
#pragma unroll
    for (int j = 0; j < 4; j++) {
      int d = wn + j * 16 + lj;
      float bias = bk[base + d];
      float freq = rope_freq(d >> 1);
      bool odd = (d & 1) != 0;
#pragma unroll
      for (int i = 0; i < 4; i++)
#pragma unroll
        for (int r = 0; r < 4; r++) {
          int mloc = wm + i * 16 + lr * 4 + r;
          int s = (m0 + mloc) & (SS - 1);
          float val = acc[i][j][r] + bias;
          float other = __shfl_xor(val, 1, 64);
          float ang = (float)s * freq;
          float cs = cosf(ang), sn = sinf(ang);
          float res = odd ? (other * sn + val * cs) : (val * cs - other * sn);
          Sm[mloc * 136 + d] = f2b(res);
        }
    }
  } else {  // V: bias, stage TRANSPOSED (d, s_loc), pitch 264 over 256 rows
    int base = n0 - 2560;
#pragma unroll
    for (int j = 0; j < 4; j++) {
      int d = wn + j * 16 + lj;
      float bias = bv[base + d];
#pragma unroll
      for (int i = 0; i < 4; i++)
#pragma unroll
        for (int r = 0; r < 4; r++) {
          int mloc = wm + i * 16 + lr * 4 + r;
          Sm[d * 264 + mloc] = f2b(acc[i][j][r] + bias);
        }
    }
  }
  __syncthreads();
  if (n0 < 2048) {
    int r0 = t >> 4, ch = t & 15;
#pragma unroll
    for (int p = 0; p < 8; p++) {
      int row = p * 32 + r0;  // s_loc in [0,256)
      *(short8*)(qbuf + (size_t)(m0 + row) * 2048 + n0 + ch * 8) =
          *(const short8*)&Sm[row * 136 + ch * 8];
    }
  } else if (n0 < 2560) {
    int r0 = t >> 4, ch = t & 15;
    int kvh = (n0 - 2048) >> 7;
    int b = m0 >> 11, s0 = m0 & (SS - 1);
    short* dst = kbuf + ((size_t)(b * KVH + kvh) * SS + s0) * HD;
#pragma unroll
    for (int p = 0; p < 8; p++) {
      int row = p * 32 + r0;  // s_loc
      *(short8*)(dst + (size_t)row * HD + ch * 8) = *(const short8*)&Sm[row * 136 + ch * 8];
    }
  } else {
    int r0 = t >> 5, ch = t & 31;  // 32 lanes x 8 shorts = 256 s-cols
    int kvh = (n0 - 2560) >> 7;
    int b = m0 >> 11, s0 = m0 & (SS - 1);
    short* dst = vtr + ((size_t)(b * KVH + kvh) * HD) * SS + s0;
#pragma unroll
    for (int p = 0; p < 8; p++) {
      int dl = p * 16 + r0;  // d in [0,128)
      *(short8*)(dst + (size_t)dl * SS + ch * 8) = *(const short8*)&Sm[dl * 264 + ch * 8];
    }
  }
}

// -------------------- flash attention (causal, GQA) --------------------
// XCD-chunked swizzle: 1024 blocks / 8 XCDs = 128-block chunks. Chunk c maps
// exactly to one (batch, kvh-group): its whole K+V working set is 1 MB,
// L2-resident across all 128 blocks of the XCD.
__global__ __launch_bounds__(256) void attn_kernel(
    const short* __restrict__ qb, const short* __restrict__ kb,
    const short* __restrict__ vt, short* __restrict__ ao) {
  __shared__ __align__(16) short Kl[64 * 128];     // (key, hd)
  __shared__ __align__(16) short Vl[128 * 64];     // (hd, key)
  __shared__ __align__(16) short Pl[4 * 16 * 64];  // per-wave P
  int t = threadIdx.x, lane = t & 63, w = t >> 6;
  int lj = lane & 15, lr = lane >> 4;
  int id = blockIdx.x + (blockIdx.y << 5) + (blockIdx.z << 9);  // 1024 blocks
  int swz = (id & 7) * 128 + (id >> 3);
  int qt = swz & 31, h = (swz >> 5) & 15, b = swz >> 9;
  int kvh = h >> 2;  // REP = 4
  int qb0 = qt * 64;
  const short* qbase = qb + (size_t)(b * SS) * 2048 + h * HD;
  const short* kbase = kb + (size_t)(b * KVH + kvh) * SS * HD;
  const short* vbase = vt + (size_t)(b * KVH + kvh) * HD * SS;
  short8 aq[4];
  int sq = qb0 + w * 16 + lj;
#pragma unroll
  for (int kk = 0; kk < 4; kk++)
    aq[kk] = *(const short8*)(qbase + (size_t)sq * 2048 + kk * 32 + lr * 8);
  f32x4 O[8] = {};
  const float NEG = -1e30f;
  float mrow[4] = {NEG, NEG, NEG, NEG};
  float lrow[4] = {0.f, 0.f, 0.f, 0.f};
  const float scale = 0.088388347648318447f;  // 1/sqrt(128)
  int nkt = qt + 1;
  for (int kt = 0; kt < nkt; ++kt) {
    short8 gk[4], gv[4];
#pragma unroll
    for (int i = 0; i < 4; i++) {
      gk[i] = *(const short8*)(kbase + (size_t)(kt * 64 + i * 16 + (t >> 4)) * HD + (t & 15) * 8);
      gv[i] = *(const short8*)(vbase + (size_t)(i * 32 + (t >> 3)) * SS + kt * 64 + (t & 7) * 8);
    }
#pragma unroll
    for (int i = 0; i < 4; i++) {
      *(short8*)&Kl[(i * 16 + (t >> 4)) * 128 + (t & 15) * 8] = gk[i];
      *(short8*)&Vl[(i * 32 + (t >> 3)) * 64 + (t & 7) * 8] = gv[i];
    }
    __syncthreads();
    f32x4 S[4];
#pragma unroll
    for (int nt = 0; nt < 4; nt++) {
      f32x4 sc = {};
#pragma unroll
      for (int kk = 0; kk < 4; kk++) {
        short8 bk_ = *(const short8*)&Kl[(nt * 16 + lj) * 128 + kk * 32 + lr * 8];
        sc = __builtin_amdgcn_mfma_f32_16x16x32_bf16(aq[kk], bk_, sc, 0, 0, 0);
      }
      S[nt] = sc;
    }
    int rowg = qb0 + w * 16 + lr * 4;
#pragma unroll
    for (int nt = 0; nt < 4; nt++) {
      int colg = kt * 64 + nt * 16 + lj;
#pragma unroll
      for (int r = 0; r < 4; r++) {
        float v = S[nt][r] * scale;
        if (colg > rowg + r) v = NEG;  // finite mask; exp underflows to 0
        S[nt][r] = v;
      }
    }
    float alpha[4];
#pragma unroll
    for (int r = 0; r < 4; r++) {
      float m_ = fmaxf(fmaxf(S[0][r], S[1][r]), fmaxf(S[2][r], S[3][r]));
#pragma unroll
      for (int off = 1; off < 16; off <<= 1) m_ = fmaxf(m_, __shfl_xor(m_, off, 64));
      float mn = fmaxf(mrow[r], m_);
      alpha[r] = __expf(mrow[r] - mn);
      mrow[r] = mn;
    }
    float ls[4] = {0.f, 0.f, 0.f, 0.f};
#pragma unroll
    for (int nt = 0; nt < 4; nt++)
#pragma unroll
      for (int r = 0; r < 4; r++) {
        float p = __expf(S[nt][r] - mrow[r]);
        ls[r] += p;
        Pl[(w * 16 + lr * 4 + r) * 64 + nt * 16 + lj] = f2b(p);
      }
#pragma unroll
    for (int r = 0; r < 4; r++) {
      float s_ = ls[r];
#pragma unroll
      for (int off = 1; off < 16; off <<= 1) s_ += __shfl_xor(s_, off, 64);
      lrow[r] = lrow[r] * alpha[r] + s_;
    }
#pragma unroll
    for (int jt = 0; jt < 8; jt++)
#pragma unroll
      for (int r = 0; r < 4; r++) O[jt][r] *= alpha[r];
#pragma unroll
    for (int kk = 0; kk < 2; kk++) {
      short8 ap = *(const short8*)&Pl[(w * 16 + lj) * 64 + kk * 32 + lr * 8];
#pragma unroll
      for (int jt = 0; jt < 8; jt++) {
        short8 bv_ = *(const short8*)&Vl[(jt * 16 + lj) * 64 + kk * 32 + lr * 8];
        O[jt] = __builtin_amdgcn_mfma_f32_16x16x32_bf16(ap, bv_, O[jt], 0, 0, 0);
      }
    }
    __syncthreads();
  }
  size_t obase = (size_t)(b * SS + qb0 + w * 16) * 2048 + h * HD;
#pragma unroll
  for (int jt = 0; jt < 8; jt++)
#pragma unroll
    for (int r = 0; r < 4; r++) {
      int row = lr * 4 + r;
      ao[obase + (size_t)row * 2048 + jt * 16 + lj] = f2b(O[jt][r] / lrow[r]);
    }
}

// -------------- output projection GEMM + bias (f32 output) --------------
// BM=256 x BN=128, 8 waves, BK=64, single-buffer (same structure as qkv).
// 256 blocks x 1.5 MB = 384 MB floor (vs 512 at 128^2). Default mapping:
// each XCD keeps its 2 A-panels L2-resident and streams B (8 MB) -- the
// cheaper direction (swizzle would stream all 16 MB of A instead).
__global__ __launch_bounds__(512, 4) void gemm_out(
    const short* __restrict__ A, const short* __restrict__ Bt,
    const float* __restrict__ bo, float* __restrict__ out) {
  __shared__ __align__(16) short Sm[24576];  // A 256x64 (32 KB) + B 128x64 (16 KB)
  short* Bl = Sm + 16384;
  const int K = EE;
  int t = threadIdx.x, lane = t & 63, w = t >> 6;
  int lj = lane & 15, lr = lane >> 4;
  int wm = (w >> 1) * 64, wn = (w & 1) * 64;
  int m0 = blockIdx.x * 256, n0 = blockIdx.y * 128;
  const short* Ab = A + (size_t)m0 * K;
  const short* Bb = Bt + (size_t)n0 * K;
  int srow = t >> 3, scol = (t & 7) * 8;
  char* ldsA = (char*)Sm + w * 1024;
  char* ldsB = (char*)Sm + 32768 + w * 1024;
  f32x4 acc[4][4] = {};
  for (int k0 = 0; k0 < K; k0 += 64) {
#pragma unroll
    for (int q = 0; q < 4; q++)
      async_load16(Ab + (size_t)(q * 64 + srow) * K + k0 + scol, ldsA + q * 8192);
#pragma unroll
    for (int q = 0; q < 2; q++)
      async_load16(Bb + (size_t)(q * 64 + srow) * K + k0 + scol, ldsB + q * 8192);
    __syncthreads();
    short8 a0[4], a1[4], b0[4], b1[4];
#pragma unroll
    for (int i = 0; i < 4; i++) {
      a0[i] = *(const short8*)&Sm[(wm + i * 16 + lj) * 64 + lr * 8];
      a1[i] = *(const short8*)&Sm[(wm + i * 16 + lj) * 64 + 32 + lr * 8];
    }
#pragma unroll
    for (int j = 0; j < 4; j++) {
      b0[j] = *(const short8*)&Bl[(wn + j * 16 + lj) * 64 + lr * 8];
      b1[j] = *(const short8*)&Bl[(wn + j * 16 + lj) * 64 + 32 + lr * 8];
    }
#pragma unroll
    for (int i = 0; i < 4; i++)
#pragma unroll
      for (int j = 0; j < 4; j++) {
        acc[i][j] = __builtin_amdgcn_mfma_f32_16x16x32_bf16(a0[i], b0[j], acc[i][j], 0, 0, 0);
        acc[i][j] = __builtin_amdgcn_mfma_f32_16x16x32_bf16(a1[i], b1[j], acc[i][j], 0, 0, 0);
      }
    __syncthreads();
  }
#pragma unroll
  for (int j = 0; j < 4; j++) {
    int n = n0 + wn + j * 16 + lj;
    float bias = bo[n];
#pragma unroll
    for (int i = 0; i < 4; i++)
#pragma unroll
      for (int r = 0; r < 4; r++) {
        int m = m0 + wm + i * 16 + lr * 4 + r;
        out[(size_t)m * 2048 + n] = acc[i][j][r] + bias;
      }
  }
}

extern "C" void kernel_launch(void* const* d_in, const int* in_sizes, int n_in,
                              void* d_out, int out_size, void* d_ws, size_t ws_size,
                              hipStream_t stream) {
  const float* x  = (const float*)d_in[0];
  const float* wq = (const float*)d_in[1];
  const float* bq = (const float*)d_in[2];
  const float* wk = (const float*)d_in[3];
  const float* bk = (const float*)d_in[4];
  const float* wv = (const float*)d_in[5];
  const float* bv = (const float*)d_in[6];
  const float* wo = (const float*)d_in[7];
  const float* bo = (const float*)d_in[8];
  float* out = (float*)d_out;  // f32 output per reference dtype

  // bf16 workspace, ~63 MB used. xb_ aliases ao_ (disjoint lifetime).
  short* W1t = (short*)d_ws;                    // 3072*2048
  short* Wot = W1t + (size_t)3072 * 2048;       // 2048*2048
  short* qb_ = Wot + (size_t)2048 * 2048;       // 4096*2048
  short* kb_ = qb_ + (size_t)4096 * 2048;       // 2*4*2048*128
  short* vt_ = kb_ + (size_t)4096 * 512;        // 2*4*128*2048
  short* ao_ = vt_ + (size_t)4096 * 512;        // 4096*2048
  short* xb_ = ao_;                             // alias (disjoint lifetime)

  dim3 tb(32, 8);
  f32_to_bf16<<<4096, 256, 0, stream>>>(x, xb_);
  transpose_f2b<<<dim3(64, 64), tb, 0, stream>>>(wq, W1t, 2048, 2048);
  transpose_f2b<<<dim3(16, 64), tb, 0, stream>>>(wk, W1t + (size_t)2048 * 2048, 2048, 512);
  transpose_f2b<<<dim3(16, 64), tb, 0, stream>>>(wv, W1t + (size_t)2560 * 2048, 2048, 512);
  transpose_f2b<<<dim3(64, 64), tb, 0, stream>>>(wo, Wot, 2048, 2048);

  gemm_qkv<<<dim3(16, 24), 512, 0, stream>>>(xb_, W1t, bq, bk, bv, qb_, kb_, vt_);
  attn_kernel<<<dim3(32, 16, 2), 256, 0, stream>>>(qb_, kb_, vt_, ao_);
  gemm_out<<<dim3(16, 16), 512, 0, stream>>>(ao_, Wot, bo, out);
}

// Round 4
// 914.017 us; speedup vs baseline: 1.9153x; 1.0752x over previous
//
#include <hip/hip_runtime.h>
#include <math.h>

// Problem constants
#define BB 2
#define SS 2048
#define EE 2048
#define HH 16
#define KVH 4
#define HD 128

typedef __attribute__((ext_vector_type(8))) short short8;
typedef __attribute__((ext_vector_type(4))) float f32x4;

__device__ __forceinline__ short f2b(float f) {
  unsigned u = __float_as_uint(f);
  unsigned r = (u + 0x7fffu + ((u >> 16) & 1u)) >> 16;
  return (short)r;
}

__device__ __forceinline__ void async_load16(const void* g, void* l) {
  __builtin_amdgcn_global_load_lds(
      (const __attribute__((address_space(1))) void*)g,
      (__attribute__((address_space(3))) void*)l, 16, 0, 0);
}

// RoPE freq replicating reference fp32 overflow: freqs[jp] = 1/theta^(2jp);
// theta^8 -> inf -> 0 (exp2f underflows likewise).
__device__ __forceinline__ float rope_freq(int jp) {
  return exp2f(-(float)(2 * jp) * 16.609640474436812f);
}

// ---------------- x: f32 -> bf16, elementwise ----------------
__global__ void f32_to_bf16(const float* __restrict__ in, short* __restrict__ out) {
  int i = (blockIdx.x * 256 + threadIdx.x) * 8;
  float4 a = *(const float4*)(in + i);
  float4 b = *(const float4*)(in + i + 4);
  short8 c;
  c[0] = f2b(a.x); c[1] = f2b(a.y); c[2] = f2b(a.z); c[3] = f2b(a.w);
  c[4] = f2b(b.x); c[5] = f2b(b.y); c[6] = f2b(b.z); c[7] = f2b(b.w);
  *(short8*)(out + i) = c;
}

// ---------------- weight transpose + f32->bf16: (K,N) f32 -> (N,K) bf16 ----
__global__ void transpose_f2b(const float* __restrict__ in, short* __restrict__ out,
                              int K, int N) {
  __shared__ short tile[32][33];
  int n0 = blockIdx.x * 32, k0 = blockIdx.y * 32;
  int tx = threadIdx.x, ty = threadIdx.y;  // 32 x 8
#pragma unroll
  for (int i = 0; i < 32; i += 8)
    tile[ty + i][tx] = f2b(in[(size_t)(k0 + ty + i) * N + n0 + tx]);
  __syncthreads();
#pragma unroll
  for (int i = 0; i < 32; i += 8)
    out[(size_t)(n0 + ty + i) * K + k0 + tx] = tile[tx][ty + i];
}

// -------------------- QKV GEMM + bias + RoPE --------------------
// R0-exact proven config (494 us @ 5.18 TB/s window BW). 128x128 tile,
// 4 waves, BK=64, single-buffer, 768 blocks = 3 blocks/CU co-resident --
// that co-residency is the saturation engine (R2's 384-block 256x128 tile
// cut bytes 36% but desaturated to 3.55 TB/s and LOST 100 us; epilogue
// boundaries force BN in {128,256}, so 768 MB fetch floor is this
// structure's roofline).
__global__ __launch_bounds__(256) void gemm_qkv(
    const short* __restrict__ A, const short* __restrict__ Bt,
    const float* __restrict__ bq, const float* __restrict__ bk,
    const float* __restrict__ bv,
    short* __restrict__ qbuf, short* __restrict__ kbuf, short* __restrict__ vtr) {
  __shared__ __align__(16) short Sm[128 * 136];  // 34816 B; K-loop uses 32 KB
  short* Al = Sm;             // 128 x 64 bf16
  short* Bl = Sm + 128 * 64;  // 128 x 64 bf16
  const int K = EE;
  int t = threadIdx.x, lane = t & 63, w = t >> 6;
  int wm = (w >> 1) * 64, wn = (w & 1) * 64;
  int m0 = blockIdx.x * 128, n0 = blockIdx.y * 128;
  const short* Ab = A + (size_t)m0 * K;
  const short* Bb = Bt + (size_t)n0 * K;
  // staging: issue q covers rows q*32+(t>>3), cols (t&7)*8 (8 lanes = 128 B row seg)
  int srow = t >> 3, scol = (t & 7) * 8;
  int lj = lane & 15, lr = lane >> 4;
  f32x4 acc[4][4] = {};
  for (int k0 = 0; k0 < K; k0 += 64) {
#pragma unroll
    for (int q = 0; q < 4; q++) {
      async_load16(Ab + (size_t)(q * 32 + srow) * K + k0 + scol,
                   (char*)Al + q * 4096 + w * 1024);
      async_load16(Bb + (size_t)(q * 32 + srow) * K + k0 + scol,
                   (char*)Bl + q * 4096 + w * 1024);
    }
    __syncthreads();
    short8 a0[4], a1[4], b0[4], b1[4];
#pragma unroll
    for (int i = 0; i < 4; i++) {
      a0[i] = *(const short8*)&Al[(wm + i * 16 + lj) * 64 + lr * 8];
      a1[i] = *(const short8*)&Al[(wm + i * 16 + lj) * 64 + 32 + lr * 8];
    }
#pragma unroll
    for (int j = 0; j < 4; j++) {
      b0[j] = *(const short8*)&Bl[(wn + j * 16 + lj) * 64 + lr * 8];
      b1[j] = *(const short8*)&Bl[(wn + j * 16 + lj) * 64 + 32 + lr * 8];
    }
#pragma unroll
    for (int i = 0; i < 4; i++)
#pragma unroll
      for (int j = 0; j < 4; j++) {
        acc[i][j] = __builtin_amdgcn_mfma_f32_16x16x32_bf16(a0[i], b0[j], acc[i][j], 0, 0, 0);
        acc[i][j] = __builtin_amdgcn_mfma_f32_16x16x32_bf16(a1[i], b1[j], acc[i][j], 0, 0, 0);
      }
    __syncthreads();
  }
  // ---- stage epilogue tile into LDS (pitch 136), then coalesced write ----
  if (n0 < 2048) {  // Q: bias + rope, row-major (s_loc, d)
#pragma unroll
    for (int j = 0; j < 4; j++) {
      int d = wn + j * 16 + lj;
      float bias = bq[n0 + d];
      float freq = rope_freq(d >> 1);
      bool odd = (d & 1) != 0;
#pragma unroll
      for (int i = 0; i < 4; i++)
#pragma unroll
        for (int r = 0; r < 4; r++) {
          int mloc = wm + i * 16 + lr * 4 + r;
          int s = (m0 + mloc) & (SS - 1);
          float val = acc[i][j][r] + bias;
          float other = __shfl_xor(val, 1, 64);
          float ang = (float)s * freq;
          float cs = cosf(ang), sn = sinf(ang);
          float res = odd ? (other * sn + val * cs) : (val * cs - other * sn);
          Sm[mloc * 136 + d] = f2b(res);
        }
    }
  } else if (n0 < 2560) {  // K: bias + rope, row-major (s_loc, d)
    int base = n0 - 2048;
#pragma unroll
    for (int j = 0; j < 4; j++) {
      int d = wn + j * 16 + lj;
      float bias = bk[base + d];
      float freq = rope_freq(d >> 1);
      bool odd = (d & 1) != 0;
#pragma unroll
      for (int i = 0; i < 4; i++)
#pragma unroll
        for (int r = 0; r < 4; r++) {
          int mloc = wm + i * 16 + lr * 4 + r;
          int s = (m0 + mloc) & (SS - 1);
          float val = acc[i][j][r] + bias;
          float other = __shfl_xor(val, 1, 64);
          float ang = (float)s * freq;
          float cs = cosf(ang), sn = sinf(ang);
          float res = odd ? (other * sn + val * cs) : (val * cs - other * sn);
          Sm[mloc * 136 + d] = f2b(res);
        }
    }
  } else {  // V: bias, stage TRANSPOSED (d, s_loc)
    int base = n0 - 2560;
#pragma unroll
    for (int j = 0; j < 4; j++) {
      int d = wn + j * 16 + lj;
      float bias = bv[base + d];
#pragma unroll
      for (int i = 0; i < 4; i++)
#pragma unroll
        for (int r = 0; r < 4; r++) {
          int mloc = wm + i * 16 + lr * 4 + r;
          Sm[d * 136 + mloc] = f2b(acc[i][j][r] + bias);
        }
    }
  }
  __syncthreads();
  int r0 = t >> 4, ch = t & 15;
  if (n0 < 2048) {
#pragma unroll
    for (int p = 0; p < 8; p++) {
      int row = p * 16 + r0;  // s_loc
      *(short8*)(qbuf + (size_t)(m0 + row) * 2048 + n0 + ch * 8) =
          *(const short8*)&Sm[row * 136 + ch * 8];
    }
  } else if (n0 < 2560) {
    int kvh = (n0 - 2048) >> 7;
    int b = m0 >> 11, s0 = m0 & (SS - 1);
    short* dst = kbuf + ((size_t)(b * KVH + kvh) * SS + s0) * HD;
#pragma unroll
    for (int p = 0; p < 8; p++) {
      int row = p * 16 + r0;  // s_loc
      *(short8*)(dst + (size_t)row * HD + ch * 8) = *(const short8*)&Sm[row * 136 + ch * 8];
    }
  } else {
    int kvh = (n0 - 2560) >> 7;
    int b = m0 >> 11, s0 = m0 & (SS - 1);
    short* dst = vtr + ((size_t)(b * KVH + kvh) * HD) * SS + s0;
#pragma unroll
    for (int p = 0; p < 8; p++) {
      int row = p * 16 + r0;  // d
      *(short8*)(dst + (size_t)row * SS + ch * 8) = *(const short8*)&Sm[row * 136 + ch * 8];
    }
  }
}

// -------------------- flash attention (causal, GQA) --------------------
// XCD-chunked swizzle: chunk c = one (batch, kvh-group); K+V working set
// 1 MB, L2-resident per XCD.
// T14 async-STAGE pipeline: after the reg->LDS write of tile kt, issue tile
// kt+1's global loads into the same regs (in-order issue makes the WAR
// safe), then cross an lgkm-only barrier (NOT __syncthreads, which drains
// vmcnt and would kill the overlap). Loads fly under QK^T+softmax+PV; the
// trailing __syncthreads drains them after completion. T5 setprio wraps
// both MFMA clusters (guide: attn +4-7%).
__global__ __launch_bounds__(256) void attn_kernel(
    const short* __restrict__ qb, const short* __restrict__ kb,
    const short* __restrict__ vt, short* __restrict__ ao) {
  __shared__ __align__(16) short Kl[64 * 128];     // (key, hd)
  __shared__ __align__(16) short Vl[128 * 64];     // (hd, key)
  __shared__ __align__(16) short Pl[4 * 16 * 64];  // per-wave P
  int t = threadIdx.x, lane = t & 63, w = t >> 6;
  int lj = lane & 15, lr = lane >> 4;
  int id = blockIdx.x + (blockIdx.y << 5) + (blockIdx.z << 9);  // 1024 blocks
  int swz = (id & 7) * 128 + (id >> 3);
  int qt = swz & 31, h = (swz >> 5) & 15, b = swz >> 9;
  int kvh = h >> 2;  // REP = 4
  int qb0 = qt * 64;
  const short* qbase = qb + (size_t)(b * SS) * 2048 + h * HD;
  const short* kbase = kb + (size_t)(b * KVH + kvh) * SS * HD;
  const short* vbase = vt + (size_t)(b * KVH + kvh) * HD * SS;
  short8 aq[4];
  int sq = qb0 + w * 16 + lj;
#pragma unroll
  for (int kk = 0; kk < 4; kk++)
    aq[kk] = *(const short8*)(qbase + (size_t)sq * 2048 + kk * 32 + lr * 8);
  f32x4 O[8] = {};
  const float NEG = -1e30f;
  float mrow[4] = {NEG, NEG, NEG, NEG};
  float lrow[4] = {0.f, 0.f, 0.f, 0.f};
  const float scale = 0.088388347648318447f;  // 1/sqrt(128)
  int nkt = qt + 1;
  // preload tile 0 into regs
  short8 gk[4], gv[4];
#pragma unroll
  for (int i = 0; i < 4; i++) {
    gk[i] = *(const short8*)(kbase + (size_t)(i * 16 + (t >> 4)) * HD + (t & 15) * 8);
    gv[i] = *(const short8*)(vbase + (size_t)(i * 32 + (t >> 3)) * SS + (t & 7) * 8);
  }
  for (int kt = 0; kt < nkt; ++kt) {
    // reg -> LDS (prev iteration's readers finished at trailing barrier)
#pragma unroll
    for (int i = 0; i < 4; i++) {
      *(short8*)&Kl[(i * 16 + (t >> 4)) * 128 + (t & 15) * 8] = gk[i];
      *(short8*)&Vl[(i * 32 + (t >> 3)) * 64 + (t & 7) * 8] = gv[i];
    }
    // issue next tile's loads now; they overlap the whole compute phase
    if (kt + 1 < nkt) {
#pragma unroll
      for (int i = 0; i < 4; i++) {
        gk[i] = *(const short8*)(kbase +
                 (size_t)((kt + 1) * 64 + i * 16 + (t >> 4)) * HD + (t & 15) * 8);
        gv[i] = *(const short8*)(vbase +
                 (size_t)(i * 32 + (t >> 3)) * SS + (kt + 1) * 64 + (t & 7) * 8);
      }
    }
    // lgkm-only barrier: LDS writes visible, global loads stay in flight
    asm volatile("s_waitcnt lgkmcnt(0)" ::: "memory");
    __builtin_amdgcn_s_barrier();
    f32x4 S[4];
    __builtin_amdgcn_s_setprio(1);
#pragma unroll
    for (int nt = 0; nt < 4; nt++) {
      f32x4 sc = {};
#pragma unroll
      for (int kk = 0; kk < 4; kk++) {
        short8 bk_ = *(const short8*)&Kl[(nt * 16 + lj) * 128 + kk * 32 + lr * 8];
        sc = __builtin_amdgcn_mfma_f32_16x16x32_bf16(aq[kk], bk_, sc, 0, 0, 0);
      }
      S[nt] = sc;
    }
    __builtin_amdgcn_s_setprio(0);
    int rowg = qb0 + w * 16 + lr * 4;
#pragma unroll
    for (int nt = 0; nt < 4; nt++) {
      int colg = kt * 64 + nt * 16 + lj;
#pragma unroll
      for (int r = 0; r < 4; r++) {
        float v = S[nt][r] * scale;
        if (colg > rowg + r) v = NEG;  // finite mask; exp underflows to 0
        S[nt][r] = v;
      }
    }
    float alpha[4];
#pragma unroll
    for (int r = 0; r < 4; r++) {
      float m_ = fmaxf(fmaxf(S[0][r], S[1][r]), fmaxf(S[2][r], S[3][r]));
#pragma unroll
      for (int off = 1; off < 16; off <<= 1) m_ = fmaxf(m_, __shfl_xor(m_, off, 64));
      float mn = fmaxf(mrow[r], m_);
      alpha[r] = __expf(mrow[r] - mn);
      mrow[r] = mn;
    }
    float ls[4] = {0.f, 0.f, 0.f, 0.f};
#pragma unroll
    for (int nt = 0; nt < 4; nt++)
#pragma unroll
      for (int r = 0; r < 4; r++) {
        float p = __expf(S[nt][r] - mrow[r]);
        ls[r] += p;
        Pl[(w * 16 + lr * 4 + r) * 64 + nt * 16 + lj] = f2b(p);
      }
#pragma unroll
    for (int r = 0; r < 4; r++) {
      float s_ = ls[r];
#pragma unroll
      for (int off = 1; off < 16; off <<= 1) s_ += __shfl_xor(s_, off, 64);
      lrow[r] = lrow[r] * alpha[r] + s_;
    }
#pragma unroll
    for (int jt = 0; jt < 8; jt++)
#pragma unroll
      for (int r = 0; r < 4; r++) O[jt][r] *= alpha[r];
    __builtin_amdgcn_s_setprio(1);
#pragma unroll
    for (int kk = 0; kk < 2; kk++) {
      short8 ap = *(const short8*)&Pl[(w * 16 + lj) * 64 + kk * 32 + lr * 8];
#pragma unroll
      for (int jt = 0; jt < 8; jt++) {
        short8 bv_ = *(const short8*)&Vl[(jt * 16 + lj) * 64 + kk * 32 + lr * 8];
        O[jt] = __builtin_amdgcn_mfma_f32_16x16x32_bf16(ap, bv_, O[jt], 0, 0, 0);
      }
    }
    __builtin_amdgcn_s_setprio(0);
    __syncthreads();
  }
  size_t obase = (size_t)(b * SS + qb0 + w * 16) * 2048 + h * HD;
#pragma unroll
  for (int jt = 0; jt < 8; jt++)
#pragma unroll
    for (int r = 0; r < 4; r++) {
      int row = lr * 4 + r;
      ao[obase + (size_t)row * 2048 + jt * 16 + lj] = f2b(O[jt][r] / lrow[r]);
    }
}

// -------------- output projection GEMM + bias (f32 output) --------------
// BM=256 x BN=128, 8 waves, BK=64, single-buffer. 256 blocks x 1.5 MB =
// 384 MB floor; measured equal-time to the 128^2 version (R2 total delta
// was fully attributable to qkv), so keep the lower-byte shape.
__global__ __launch_bounds__(512, 4) void gemm_out(
    const short* __restrict__ A, const short* __restrict__ Bt,
    const float* __restrict__ bo, float* __restrict__ out) {
  __shared__ __align__(16) short Sm[24576];  // A 256x64 (32 KB) + B 128x64 (16 KB)
  short* Bl = Sm + 16384;
  const int K = EE;
  int t = threadIdx.x, lane = t & 63, w = t >> 6;
  int lj = lane & 15, lr = lane >> 4;
  int wm = (w >> 1) * 64, wn = (w & 1) * 64;
  int m0 = blockIdx.x * 256, n0 = blockIdx.y * 128;
  const short* Ab = A + (size_t)m0 * K;
  const short* Bb = Bt + (size_t)n0 * K;
  int srow = t >> 3, scol = (t & 7) * 8;
  char* ldsA = (char*)Sm + w * 1024;
  char* ldsB = (char*)Sm + 32768 + w * 1024;
  f32x4 acc[4][4] = {};
  for (int k0 = 0; k0 < K; k0 += 64) {
#pragma unroll
    for (int q = 0; q < 4; q++)
      async_load16(Ab + (size_t)(q * 64 + srow) * K + k0 + scol, ldsA + q * 8192);
#pragma unroll
    for (int q = 0; q < 2; q++)
      async_load16(Bb + (size_t)(q * 64 + srow) * K + k0 + scol, ldsB + q * 8192);
    __syncthreads();
    short8 a0[4], a1[4], b0[4], b1[4];
#pragma unroll
    for (int i = 0; i < 4; i++) {
      a0[i] = *(const short8*)&Sm[(wm + i * 16 + lj) * 64 + lr * 8];
      a1[i] = *(const short8*)&Sm[(wm + i * 16 + lj) * 64 + 32 + lr * 8];
    }
#pragma unroll
    for (int j = 0; j < 4; j++) {
      b0[j] = *(const short8*)&Bl[(wn + j * 16 + lj) * 64 + lr * 8];
      b1[j] = *(const short8*)&Bl[(wn + j * 16 + lj) * 64 + 32 + lr * 8];
    }
#pragma unroll
    for (int i = 0; i < 4; i++)
#pragma unroll
      for (int j = 0; j < 4; j++) {
        acc[i][j] = __builtin_amdgcn_mfma_f32_16x16x32_bf16(a0[i], b0[j], acc[i][j], 0, 0, 0);
        acc[i][j] = __builtin_amdgcn_mfma_f32_16x16x32_bf16(a1[i], b1[j], acc[i][j], 0, 0, 0);
      }
    __syncthreads();
  }
#pragma unroll
  for (int j = 0; j < 4; j++) {
    int n = n0 + wn + j * 16 + lj;
    float bias = bo[n];
#pragma unroll
    for (int i = 0; i < 4; i++)
#pragma unroll
      for (int r = 0; r < 4; r++) {
        int m = m0 + wm + i * 16 + lr * 4 + r;
        out[(size_t)m * 2048 + n] = acc[i][j][r] + bias;
      }
  }
}

extern "C" void kernel_launch(void* const* d_in, const int* in_sizes, int n_in,
                              void* d_out, int out_size, void* d_ws, size_t ws_size,
                              hipStream_t stream) {
  const float* x  = (const float*)d_in[0];
  const float* wq = (const float*)d_in[1];
  const float* bq = (const float*)d_in[2];
  const float* wk = (const float*)d_in[3];
  const float* bk = (const float*)d_in[4];
  const float* wv = (const float*)d_in[5];
  const float* bv = (const float*)d_in[6];
  const float* wo = (const float*)d_in[7];
  const float* bo = (const float*)d_in[8];
  float* out = (float*)d_out;  // f32 output per reference dtype

  // bf16 workspace, ~63 MB used. xb_ aliases ao_ (disjoint lifetime).
  short* W1t = (short*)d_ws;                    // 3072*2048
  short* Wot = W1t + (size_t)3072 * 2048;       // 2048*2048
  short* qb_ = Wot + (size_t)2048 * 2048;       // 4096*2048
  short* kb_ = qb_ + (size_t)4096 * 2048;       // 2*4*2048*128
  short* vt_ = kb_ + (size_t)4096 * 512;        // 2*4*128*2048
  short* ao_ = vt_ + (size_t)4096 * 512;        // 4096*2048
  short* xb_ = ao_;                             // alias (disjoint lifetime)

  dim3 tb(32, 8);
  f32_to_bf16<<<4096, 256, 0, stream>>>(x, xb_);
  transpose_f2b<<<dim3(64, 64), tb, 0, stream>>>(wq, W1t, 2048, 2048);
  transpose_f2b<<<dim3(16, 64), tb, 0, stream>>>(wk, W1t + (size_t)2048 * 2048, 2048, 512);
  transpose_f2b<<<dim3(16, 64), tb, 0, stream>>>(wv, W1t + (size_t)2560 * 2048, 2048, 512);
  transpose_f2b<<<dim3(64, 64), tb, 0, stream>>>(wo, Wot, 2048, 2048);

  gemm_qkv<<<dim3(32, 24), 256, 0, stream>>>(xb_, W1t, bq, bk, bv, qb_, kb_, vt_);
  attn_kernel<<<dim3(32, 16, 2), 256, 0, stream>>>(qb_, kb_, vt_, ao_);
  gemm_out<<<dim3(16, 16), 512, 0, stream>>>(ao_, Wot, bo, out);
}

// Round 5
// 890.442 us; speedup vs baseline: 1.9660x; 1.0265x over previous
//
#include <hip/hip_runtime.h>
#include <math.h>

// Problem constants
#define BB 2
#define SS 2048
#define EE 2048
#define HH 16
#define KVH 4
#define HD 128

typedef __attribute__((ext_vector_type(8))) short short8;
typedef __attribute__((ext_vector_type(4))) float f32x4;

__device__ __forceinline__ short f2b(float f) {
  unsigned u = __float_as_uint(f);
  unsigned r = (u + 0x7fffu + ((u >> 16) & 1u)) >> 16;
  return (short)r;
}

__device__ __forceinline__ void async_load16(const void* g, void* l) {
  __builtin_amdgcn_global_load_lds(
      (const __attribute__((address_space(1))) void*)g,
      (__attribute__((address_space(3))) void*)l, 16, 0, 0);
}

// RoPE freq replicating reference fp32 overflow: freqs[jp] = 1/theta^(2jp);
// theta^8 -> inf -> 0 (exp2f underflows likewise).
__device__ __forceinline__ float rope_freq(int jp) {
  return exp2f(-(float)(2 * jp) * 16.609640474436812f);
}

// ---------------- x: f32 -> bf16, elementwise ----------------
__global__ void f32_to_bf16(const float* __restrict__ in, short* __restrict__ out) {
  int i = (blockIdx.x * 256 + threadIdx.x) * 8;
  float4 a = *(const float4*)(in + i);
  float4 b = *(const float4*)(in + i + 4);
  short8 c;
  c[0] = f2b(a.x); c[1] = f2b(a.y); c[2] = f2b(a.z); c[3] = f2b(a.w);
  c[4] = f2b(b.x); c[5] = f2b(b.y); c[6] = f2b(b.z); c[7] = f2b(b.w);
  *(short8*)(out + i) = c;
}

// ---------------- weight transpose + f32->bf16: (K,N) f32 -> (N,K) bf16 ----
__global__ void transpose_f2b(const float* __restrict__ in, short* __restrict__ out,
                              int K, int N) {
  __shared__ short tile[32][33];
  int n0 = blockIdx.x * 32, k0 = blockIdx.y * 32;
  int tx = threadIdx.x, ty = threadIdx.y;  // 32 x 8
#pragma unroll
  for (int i = 0; i < 32; i += 8)
    tile[ty + i][tx] = f2b(in[(size_t)(k0 + ty + i) * N + n0 + tx]);
  __syncthreads();
#pragma unroll
  for (int i = 0; i < 32; i += 8)
    out[(size_t)(n0 + ty + i) * K + k0 + tx] = tile[tx][ty + i];
}

// -------------------- QKV GEMM + bias + RoPE --------------------
// R0-exact proven config (492-494 us @ 5.2 TB/s window BW, 3x measured).
// 128x128 tile, 4 waves, BK=64, single-buffer, 768 blocks = ~3 blocks/CU
// co-resident -- the saturation engine. Byte floor at this tile = 768 MB
// fetch; duration == (fetch + fixed background writes)/5.2 TB/s.
__global__ __launch_bounds__(256) void gemm_qkv(
    const short* __restrict__ A, const short* __restrict__ Bt,
    const float* __restrict__ bq, const float* __restrict__ bk,
    const float* __restrict__ bv,
    short* __restrict__ qbuf, short* __restrict__ kbuf, short* __restrict__ vtr) {
  __shared__ __align__(16) short Sm[128 * 136];  // 34816 B; K-loop uses 32 KB
  short* Al = Sm;             // 128 x 64 bf16
  short* Bl = Sm + 128 * 64;  // 128 x 64 bf16
  const int K = EE;
  int t = threadIdx.x, lane = t & 63, w = t >> 6;
  int wm = (w >> 1) * 64, wn = (w & 1) * 64;
  int m0 = blockIdx.x * 128, n0 = blockIdx.y * 128;
  const short* Ab = A + (size_t)m0 * K;
  const short* Bb = Bt + (size_t)n0 * K;
  // staging: issue q covers rows q*32+(t>>3), cols (t&7)*8 (8 lanes = 128 B row seg)
  int srow = t >> 3, scol = (t & 7) * 8;
  int lj = lane & 15, lr = lane >> 4;
  f32x4 acc[4][4] = {};
  for (int k0 = 0; k0 < K; k0 += 64) {
#pragma unroll
    for (int q = 0; q < 4; q++) {
      async_load16(Ab + (size_t)(q * 32 + srow) * K + k0 + scol,
                   (char*)Al + q * 4096 + w * 1024);
      async_load16(Bb + (size_t)(q * 32 + srow) * K + k0 + scol,
                   (char*)Bl + q * 4096 + w * 1024);
    }
    __syncthreads();
    short8 a0[4], a1[4], b0[4], b1[4];
#pragma unroll
    for (int i = 0; i < 4; i++) {
      a0[i] = *(const short8*)&Al[(wm + i * 16 + lj) * 64 + lr * 8];
      a1[i] = *(const short8*)&Al[(wm + i * 16 + lj) * 64 + 32 + lr * 8];
    }
#pragma unroll
    for (int j = 0; j < 4; j++) {
      b0[j] = *(const short8*)&Bl[(wn + j * 16 + lj) * 64 + lr * 8];
      b1[j] = *(const short8*)&Bl[(wn + j * 16 + lj) * 64 + 32 + lr * 8];
    }
#pragma unroll
    for (int i = 0; i < 4; i++)
#pragma unroll
      for (int j = 0; j < 4; j++) {
        acc[i][j] = __builtin_amdgcn_mfma_f32_16x16x32_bf16(a0[i], b0[j], acc[i][j], 0, 0, 0);
        acc[i][j] = __builtin_amdgcn_mfma_f32_16x16x32_bf16(a1[i], b1[j], acc[i][j], 0, 0, 0);
      }
    __syncthreads();
  }
  // ---- stage epilogue tile into LDS (pitch 136), then coalesced write ----
  if (n0 < 2048) {  // Q: bias + rope, row-major (s_loc, d)
#pragma unroll
    for (int j = 0; j < 4; j++) {
      int d = wn + j * 16 + lj;
      float bias = bq[n0 + d];
      float freq = rope_freq(d >> 1);
      bool odd = (d & 1) != 0;
#pragma unroll
      for (int i = 0; i < 4; i++)
#pragma unroll
        for (int r = 0; r < 4; r++) {
          int mloc = wm + i * 16 + lr * 4 + r;
          int s = (m0 + mloc) & (SS - 1);
          float val = acc[i][j][r] + bias;
          float other = __shfl_xor(val, 1, 64);
          float ang = (float)s * freq;
          float cs = cosf(ang), sn = sinf(ang);
          float res = odd ? (other * sn + val * cs) : (val * cs - other * sn);
          Sm[mloc * 136 + d] = f2b(res);
        }
    }
  } else if (n0 < 2560) {  // K: bias + rope, row-major (s_loc, d)
    int base = n0 - 2048;
#pragma unroll
    for (int j = 0; j < 4; j++) {
      int d = wn + j * 16 + lj;
      float bias = bk[base + d];
      float freq = rope_freq(d >> 1);
      bool odd = (d & 1) != 0;
#pragma unroll
      for (int i = 0; i < 4; i++)
#pragma unroll
        for (int r = 0; r < 4; r++) {
          int mloc = wm + i * 16 + lr * 4 + r;
          int s = (m0 + mloc) & (SS - 1);
          float val = acc[i][j][r] + bias;
          float other = __shfl_xor(val, 1, 64);
          float ang = (float)s * freq;
          float cs = cosf(ang), sn = sinf(ang);
          float res = odd ? (other * sn + val * cs) : (val * cs - other * sn);
          Sm[mloc * 136 + d] = f2b(res);
        }
    }
  } else {  // V: bias, stage TRANSPOSED (d, s_loc)
    int base = n0 - 2560;
#pragma unroll
    for (int j = 0; j < 4; j++) {
      int d = wn + j * 16 + lj;
      float bias = bv[base + d];
#pragma unroll
      for (int i = 0; i < 4; i++)
#pragma unroll
        for (int r = 0; r < 4; r++) {
          int mloc = wm + i * 16 + lr * 4 + r;
          Sm[d * 136 + mloc] = f2b(acc[i][j][r] + bias);
        }
    }
  }
  __syncthreads();
  int r0 = t >> 4, ch = t & 15;
  if (n0 < 2048) {
#pragma unroll
    for (int p = 0; p < 8; p++) {
      int row = p * 16 + r0;  // s_loc
      *(short8*)(qbuf + (size_t)(m0 + row) * 2048 + n0 + ch * 8) =
          *(const short8*)&Sm[row * 136 + ch * 8];
    }
  } else if (n0 < 2560) {
    int kvh = (n0 - 2048) >> 7;
    int b = m0 >> 11, s0 = m0 & (SS - 1);
    short* dst = kbuf + ((size_t)(b * KVH + kvh) * SS + s0) * HD;
#pragma unroll
    for (int p = 0; p < 8; p++) {
      int row = p * 16 + r0;  // s_loc
      *(short8*)(dst + (size_t)row * HD + ch * 8) = *(const short8*)&Sm[row * 136 + ch * 8];
    }
  } else {
    int kvh = (n0 - 2560) >> 7;
    int b = m0 >> 11, s0 = m0 & (SS - 1);
    short* dst = vtr + ((size_t)(b * KVH + kvh) * HD) * SS + s0;
#pragma unroll
    for (int p = 0; p < 8; p++) {
      int row = p * 16 + r0;  // d
      *(short8*)(dst + (size_t)row * SS + ch * 8) = *(const short8*)&Sm[row * 136 + ch * 8];
    }
  }
}

// -------------------- flash attention (causal, GQA) --------------------
// R1-bench-exact version (measured as part of the 387-390 us "rest").
// XCD-chunked swizzle: chunk c = one (batch, kvh-group); K+V working set
// 1 MB, L2-resident per XCD. Plain serial loop: R3's T14 reg-staging
// (+32 VGPR live) + setprio on this 4-wave lockstep block cost ~35 us --
// reverted.
__global__ __launch_bounds__(256) void attn_kernel(
    const short* __restrict__ qb, const short* __restrict__ kb,
    const short* __restrict__ vt, short* __restrict__ ao) {
  __shared__ __align__(16) short Kl[64 * 128];     // (key, hd)
  __shared__ __align__(16) short Vl[128 * 64];     // (hd, key)
  __shared__ __align__(16) short Pl[4 * 16 * 64];  // per-wave P
  int t = threadIdx.x, lane = t & 63, w = t >> 6;
  int lj = lane & 15, lr = lane >> 4;
  int id = blockIdx.x + (blockIdx.y << 5) + (blockIdx.z << 9);  // 1024 blocks
  int swz = (id & 7) * 128 + (id >> 3);
  int qt = swz & 31, h = (swz >> 5) & 15, b = swz >> 9;
  int kvh = h >> 2;  // REP = 4
  int qb0 = qt * 64;
  const short* qbase = qb + (size_t)(b * SS) * 2048 + h * HD;
  const short* kbase = kb + (size_t)(b * KVH + kvh) * SS * HD;
  const short* vbase = vt + (size_t)(b * KVH + kvh) * HD * SS;
  short8 aq[4];
  int sq = qb0 + w * 16 + lj;
#pragma unroll
  for (int kk = 0; kk < 4; kk++)
    aq[kk] = *(const short8*)(qbase + (size_t)sq * 2048 + kk * 32 + lr * 8);
  f32x4 O[8] = {};
  const float NEG = -1e30f;
  float mrow[4] = {NEG, NEG, NEG, NEG};
  float lrow[4] = {0.f, 0.f, 0.f, 0.f};
  const float scale = 0.088388347648318447f;  // 1/sqrt(128)
  int nkt = qt + 1;
  for (int kt = 0; kt < nkt; ++kt) {
    short8 gk[4], gv[4];
#pragma unroll
    for (int i = 0; i < 4; i++) {
      gk[i] = *(const short8*)(kbase + (size_t)(kt * 64 + i * 16 + (t >> 4)) * HD + (t & 15) * 8);
      gv[i] = *(const short8*)(vbase + (size_t)(i * 32 + (t >> 3)) * SS + kt * 64 + (t & 7) * 8);
    }
#pragma unroll
    for (int i = 0; i < 4; i++) {
      *(short8*)&Kl[(i * 16 + (t >> 4)) * 128 + (t & 15) * 8] = gk[i];
      *(short8*)&Vl[(i * 32 + (t >> 3)) * 64 + (t & 7) * 8] = gv[i];
    }
    __syncthreads();
    f32x4 S[4];
#pragma unroll
    for (int nt = 0; nt < 4; nt++) {
      f32x4 sc = {};
#pragma unroll
      for (int kk = 0; kk < 4; kk++) {
        short8 bk_ = *(const short8*)&Kl[(nt * 16 + lj) * 128 + kk * 32 + lr * 8];
        sc = __builtin_amdgcn_mfma_f32_16x16x32_bf16(aq[kk], bk_, sc, 0, 0, 0);
      }
      S[nt] = sc;
    }
    int rowg = qb0 + w * 16 + lr * 4;
#pragma unroll
    for (int nt = 0; nt < 4; nt++) {
      int colg = kt * 64 + nt * 16 + lj;
#pragma unroll
      for (int r = 0; r < 4; r++) {
        float v = S[nt][r] * scale;
        if (colg > rowg + r) v = NEG;  // finite mask; exp underflows to 0
        S[nt][r] = v;
      }
    }
    float alpha[4];
#pragma unroll
    for (int r = 0; r < 4; r++) {
      float m_ = fmaxf(fmaxf(S[0][r], S[1][r]), fmaxf(S[2][r], S[3][r]));
#pragma unroll
      for (int off = 1; off < 16; off <<= 1) m_ = fmaxf(m_, __shfl_xor(m_, off, 64));
      float mn = fmaxf(mrow[r], m_);
      alpha[r] = __expf(mrow[r] - mn);
      mrow[r] = mn;
    }
    float ls[4] = {0.f, 0.f, 0.f, 0.f};
#pragma unroll
    for (int nt = 0; nt < 4; nt++)
#pragma unroll
      for (int r = 0; r < 4; r++) {
        float p = __expf(S[nt][r] - mrow[r]);
        ls[r] += p;
        Pl[(w * 16 + lr * 4 + r) * 64 + nt * 16 + lj] = f2b(p);
      }
#pragma unroll
    for (int r = 0; r < 4; r++) {
      float s_ = ls[r];
#pragma unroll
      for (int off = 1; off < 16; off <<= 1) s_ += __shfl_xor(s_, off, 64);
      lrow[r] = lrow[r] * alpha[r] + s_;
    }
#pragma unroll
    for (int jt = 0; jt < 8; jt++)
#pragma unroll
      for (int r = 0; r < 4; r++) O[jt][r] *= alpha[r];
#pragma unroll
    for (int kk = 0; kk < 2; kk++) {
      short8 ap = *(const short8*)&Pl[(w * 16 + lj) * 64 + kk * 32 + lr * 8];
#pragma unroll
      for (int jt = 0; jt < 8; jt++) {
        short8 bv_ = *(const short8*)&Vl[(jt * 16 + lj) * 64 + kk * 32 + lr * 8];
        O[jt] = __builtin_amdgcn_mfma_f32_16x16x32_bf16(ap, bv_, O[jt], 0, 0, 0);
      }
    }
    __syncthreads();
  }
  size_t obase = (size_t)(b * SS + qb0 + w * 16) * 2048 + h * HD;
#pragma unroll
  for (int jt = 0; jt < 8; jt++)
#pragma unroll
    for (int r = 0; r < 4; r++) {
      int row = lr * 4 + r;
      ao[obase + (size_t)row * 2048 + jt * 16 + lj] = f2b(O[jt][r] / lrow[r]);
    }
}

// -------------- output projection GEMM + bias (f32 output) --------------
// BM=256 x BN=128, 8 waves, BK=64, single-buffer. 256 blocks x 1.5 MB =
// 384 MB floor; measured equal-time to the swizzled 128^2 version twice
// (R2/R3 "rest" = 387 us both), so keep the lower-byte shape.
__global__ __launch_bounds__(512, 4) void gemm_out(
    const short* __restrict__ A, const short* __restrict__ Bt,
    const float* __restrict__ bo, float* __restrict__ out) {
  __shared__ __align__(16) short Sm[24576];  // A 256x64 (32 KB) + B 128x64 (16 KB)
  short* Bl = Sm + 16384;
  const int K = EE;
  int t = threadIdx.x, lane = t & 63, w = t >> 6;
  int lj = lane & 15, lr = lane >> 4;
  int wm = (w >> 1) * 64, wn = (w & 1) * 64;
  int m0 = blockIdx.x * 256, n0 = blockIdx.y * 128;
  const short* Ab = A + (size_t)m0 * K;
  const short* Bb = Bt + (size_t)n0 * K;
  int srow = t >> 3, scol = (t & 7) * 8;
  char* ldsA = (char*)Sm + w * 1024;
  char* ldsB = (char*)Sm + 32768 + w * 1024;
  f32x4 acc[4][4] = {};
  for (int k0 = 0; k0 < K; k0 += 64) {
#pragma unroll
    for (int q = 0; q < 4; q++)
      async_load16(Ab + (size_t)(q * 64 + srow) * K + k0 + scol, ldsA + q * 8192);
#pragma unroll
    for (int q = 0; q < 2; q++)
      async_load16(Bb + (size_t)(q * 64 + srow) * K + k0 + scol, ldsB + q * 8192);
    __syncthreads();
    short8 a0[4], a1[4], b0[4], b1[4];
#pragma unroll
    for (int i = 0; i < 4; i++) {
      a0[i] = *(const short8*)&Sm[(wm + i * 16 + lj) * 64 + lr * 8];
      a1[i] = *(const short8*)&Sm[(wm + i * 16 + lj) * 64 + 32 + lr * 8];
    }
#pragma unroll
    for (int j = 0; j < 4; j++) {
      b0[j] = *(const short8*)&Bl[(wn + j * 16 + lj) * 64 + lr * 8];
      b1[j] = *(const short8*)&Bl[(wn + j * 16 + lj) * 64 + 32 + lr * 8];
    }
#pragma unroll
    for (int i = 0; i < 4; i++)
#pragma unroll
      for (int j = 0; j < 4; j++) {
        acc[i][j] = __builtin_amdgcn_mfma_f32_16x16x32_bf16(a0[i], b0[j], acc[i][j], 0, 0, 0);
        acc[i][j] = __builtin_amdgcn_mfma_f32_16x16x32_bf16(a1[i], b1[j], acc[i][j], 0, 0, 0);
      }
    __syncthreads();
  }
#pragma unroll
  for (int j = 0; j < 4; j++) {
    int n = n0 + wn + j * 16 + lj;
    float bias = bo[n];
#pragma unroll
    for (int i = 0; i < 4; i++)
#pragma unroll
      for (int r = 0; r < 4; r++) {
        int m = m0 + wm + i * 16 + lr * 4 + r;
        out[(size_t)m * 2048 + n] = acc[i][j][r] + bias;
      }
  }
}

extern "C" void kernel_launch(void* const* d_in, const int* in_sizes, int n_in,
                              void* d_out, int out_size, void* d_ws, size_t ws_size,
                              hipStream_t stream) {
  const float* x  = (const float*)d_in[0];
  const float* wq = (const float*)d_in[1];
  const float* bq = (const float*)d_in[2];
  const float* wk = (const float*)d_in[3];
  const float* bk = (const float*)d_in[4];
  const float* wv = (const float*)d_in[5];
  const float* bv = (const float*)d_in[6];
  const float* wo = (const float*)d_in[7];
  const float* bo = (const float*)d_in[8];
  float* out = (float*)d_out;  // f32 output per reference dtype

  // bf16 workspace, ~63 MB used. xb_ aliases ao_ (disjoint lifetime).
  short* W1t = (short*)d_ws;                    // 3072*2048
  short* Wot = W1t + (size_t)3072 * 2048;       // 2048*2048
  short* qb_ = Wot + (size_t)2048 * 2048;       // 4096*2048
  short* kb_ = qb_ + (size_t)4096 * 2048;       // 2*4*2048*128
  short* vt_ = kb_ + (size_t)4096 * 512;        // 2*4*128*2048
  short* ao_ = vt_ + (size_t)4096 * 512;        // 4096*2048
  short* xb_ = ao_;                             // alias (disjoint lifetime)

  dim3 tb(32, 8);
  f32_to_bf16<<<4096, 256, 0, stream>>>(x, xb_);
  transpose_f2b<<<dim3(64, 64), tb, 0, stream>>>(wq, W1t, 2048, 2048);
  transpose_f2b<<<dim3(16, 64), tb, 0, stream>>>(wk, W1t + (size_t)2048 * 2048, 2048, 512);
  transpose_f2b<<<dim3(16, 64), tb, 0, stream>>>(wv, W1t + (size_t)2560 * 2048, 2048, 512);
  transpose_f2b<<<dim3(64, 64), tb, 0, stream>>>(wo, Wot, 2048, 2048);

  gemm_qkv<<<dim3(32, 24), 256, 0, stream>>>(xb_, W1t, bq, bk, bv, qb_, kb_, vt_);
  attn_kernel<<<dim3(32, 16, 2), 256, 0, stream>>>(qb_, kb_, vt_, ao_);
  gemm_out<<<dim3(16, 16), 512, 0, stream>>>(ao_, Wot, bo, out);
}